// Round 4
// baseline (1600.117 us; speedup 1.0000x reference)
//
#include <hip/hip_runtime.h>

// Problem constants (match reference)
#define D_   41
#define H_   159
#define W_   159
#define MD   20
#define MH   79
#define MW   79
#define CIN  32
#define COUT 64
#define BATCH 2

#define NTAP 27
#define WPK  (NTAP * 16 * 64)   // packed weights: [tap][ci/2][co], u32 = 2×bf16

typedef unsigned int u32;

static __device__ __forceinline__ u32 bf16_rn(float x) {
    u32 u = __float_as_uint(x);
    return (u + 0x7fffu + ((u >> 16) & 1u)) >> 16;   // round-to-nearest-even
}
static __device__ __forceinline__ float bf_lo(u32 p) { return __uint_as_float(p << 16); }
static __device__ __forceinline__ float bf_hi(u32 p) { return __uint_as_float(p & 0xffff0000u); }

// Pack w1/w2 (fp32 [tap][ci][co]) -> bf16-pair [tap][ci/2][co].
__global__ void pack_kernel(const float* __restrict__ w1, const float* __restrict__ w2,
                            u32* __restrict__ w1p, u32* __restrict__ w2p) {
    int i = blockIdx.x * 256 + threadIdx.x;
    if (i >= WPK) return;
    int co = i & 63, j = (i >> 6) & 15, t = i >> 10;
    int s0 = (t * 32 + 2 * j) * 64 + co;
    int s1 = (t * 32 + 2 * j + 1) * 64 + co;
    w1p[i] = bf16_rn(w1[s0]) | (bf16_rn(w1[s1]) << 16);
    w2p[i] = bf16_rn(w2[s0]) | (bf16_rn(w2[s1]) << 16);
}

// Scatter point index into dense idx grid (-1 = empty).
__global__ void scatter_idx_kernel(const int* __restrict__ coors,
                                   int* __restrict__ idx, int n) {
    int i = blockIdx.x * blockDim.x + threadIdx.x;
    if (i >= n) return;
    int4 c = ((const int4*)coors)[i];
    idx[((c.x * D_ + c.y) * H_ + c.z) * W_ + c.w] = i;
}

// mid[b,zo,yo,xo,co]: one wave per voxel (grid-stride chunks), lane = co.
// w1 staged in LDS as bf16 pairs; 27-tap lane-parallel probe + ballot loop.
__global__ __launch_bounds__(1024, 4) void mid_kernel(const float* __restrict__ feat,
                                                      const int* __restrict__ idx,
                                                      const u32* __restrict__ w1p,
                                                      float* __restrict__ mid) {
    __shared__ u32 lw[WPK];                      // 110,592 B
    for (int i = threadIdx.x; i < WPK; i += 1024) lw[i] = w1p[i];
    __syncthreads();

    const int NV = BATCH * MD * MH * MW;
    int lane = threadIdx.x & 63;
    int wid  = threadIdx.x >> 6;
    int nw   = gridDim.x * 16;
    int gw   = blockIdx.x * 16 + wid;
    int per  = (NV + nw - 1) / nw;
    int v0   = gw * per;
    int v1   = v0 + per; if (v1 > NV) v1 = NV;

    // Per-lane tap decode (lanes 0..26 probe).
    int l  = lane < NTAP ? lane : NTAP - 1;
    int kz = l / 9, kr = l % 9, ky = kr / 3, kx = kr % 3;

    for (int v = v0; v < v1; ++v) {
        int xo = v % MW; int t0 = v / MW;
        int yo = t0 % MH; t0 /= MH;
        int zo = t0 % MD; int b = t0 / MD;

        int p = -1;
        if (lane < NTAP)
            p = idx[((b * D_ + 2 * zo + kz) * H_ + 2 * yo + ky) * W_ + 2 * xo + kx];
        unsigned long long m = __ballot(p >= 0);

        float acc0 = 0.f, acc1 = 0.f;
        while (m) {
            int t = __builtin_ctzll(m);
            m &= m - 1;
            int pp = __shfl(p, t);                       // broadcast point index
            const float4* f4 = (const float4*)(feat + (size_t)pp * CIN);
            const u32* w = lw + t * (16 * 64) + lane;
            #pragma unroll
            for (int jq = 0; jq < 8; ++jq) {
                float4 f = f4[jq];                        // 16B broadcast load
                u32 pw0 = w[(2 * jq + 0) * 64];           // ci 4jq, 4jq+1
                u32 pw1 = w[(2 * jq + 1) * 64];           // ci 4jq+2, 4jq+3
                acc0 = fmaf(f.x, bf_lo(pw0), acc0);
                acc1 = fmaf(f.y, bf_hi(pw0), acc1);
                acc0 = fmaf(f.z, bf_lo(pw1), acc0);
                acc1 = fmaf(f.w, bf_hi(pw1), acc1);
            }
        }
        mid[(size_t)v * COUT + lane] = acc0 + acc1;
    }
}

// out at masked voxels: one wave per point (grid-stride chunks), lane = co.
// w2 from LDS; per-point acc[32] (ci) reduced across lanes via shfl reduce-scatter.
__global__ __launch_bounds__(1024, 4) void out_kernel(const int* __restrict__ coors,
                                                      const float* __restrict__ mid,
                                                      const u32* __restrict__ w2p,
                                                      float* __restrict__ out, int n) {
    __shared__ u32 lw[WPK];                      // 110,592 B
    for (int i = threadIdx.x; i < WPK; i += 1024) lw[i] = w2p[i];
    __syncthreads();

    int lane = threadIdx.x & 63;
    int wid  = threadIdx.x >> 6;
    int nw   = gridDim.x * 16;
    int gw   = blockIdx.x * 16 + wid;
    int per  = (n + nw - 1) / nw;
    int i0   = gw * per;
    int i1   = i0 + per; if (i1 > n) i1 = n;

    int l  = lane < NTAP ? lane : NTAP - 1;
    int kz = l / 9, kr = l % 9, ky = kr / 3, kx = kr % 3;

    for (int i = i0; i < i1; ++i) {
        int4 c = ((const int4*)coors)[i];
        int b = c.x, z = c.y, y = c.z, x = c.w;

        int zr = z - kz, yr = y - ky, xr = x - kx;
        bool ok = (lane < NTAP) &&
                  zr >= 0 && !(zr & 1) && (zr >> 1) < MD &&
                  yr >= 0 && !(yr & 1) && (yr >> 1) < MH &&
                  xr >= 0 && !(xr & 1) && (xr >> 1) < MW;
        int vv = ok ? ((b * MD + (zr >> 1)) * MH + (yr >> 1)) * MW + (xr >> 1) : -1;
        unsigned long long m = __ballot(ok);

        float acc[CIN];
        #pragma unroll
        for (int ci = 0; ci < CIN; ++ci) acc[ci] = 0.f;

        while (m) {
            int t = __builtin_ctzll(m);
            m &= m - 1;
            int v = __shfl(vv, t);
            float mr = mid[(size_t)v * COUT + lane];      // coalesced 256B
            const u32* w = lw + t * (16 * 64) + lane;
            #pragma unroll
            for (int j = 0; j < 16; ++j) {
                u32 pw = w[j * 64];
                acc[2 * j + 0] = fmaf(mr, bf_lo(pw), acc[2 * j + 0]);
                acc[2 * j + 1] = fmaf(mr, bf_hi(pw), acc[2 * j + 1]);
            }
        }

        // Reduce-scatter over 64 lanes: after 5 exchange steps lane holds one ci.
        #pragma unroll
        for (int mk = 32, half = 16; mk >= 2; mk >>= 1, half >>= 1) {
            bool up = (lane & mk) != 0;
            #pragma unroll
            for (int k = 0; k < 16; ++k) {
                if (k >= half) break;
                float send = acc[up ? k : k + half];
                float keep = acc[up ? k + half : k];
                float recv = __shfl_xor(send, mk, 64);
                acc[k] = keep + recv;
            }
        }
        float s = acc[0] + __shfl_xor(acc[0], 1, 64);
        int ci = lane >> 1;   // ci index held by this lane pair
        if ((lane & 1) == 0)
            out[((size_t)(b * CIN + ci) * D_ + z) * (H_ * W_) + (size_t)y * W_ + x] = s;
    }
}

extern "C" void kernel_launch(void* const* d_in, const int* in_sizes, int n_in,
                              void* d_out, int out_size, void* d_ws, size_t ws_size,
                              hipStream_t stream) {
    const float* feat  = (const float*)d_in[0];
    const int*   coors = (const int*)d_in[1];
    const float* w1    = (const float*)d_in[3];
    const float* w2    = (const float*)d_in[4];
    float*       out   = (float*)d_out;

    int n = in_sizes[0] / CIN;   // 150000 points total

    // Workspace: [idx 8.3MB][mid 64MB][w1p 110KB][w2p 110KB]
    int*   idx      = (int*)d_ws;
    size_t idxBytes = (size_t)BATCH * D_ * H_ * W_ * sizeof(int);
    size_t midOff   = (idxBytes + 255) & ~(size_t)255;
    float* mid      = (float*)((char*)d_ws + midOff);
    size_t wOff     = midOff + (size_t)BATCH * MD * MH * MW * COUT * sizeof(float);
    wOff            = (wOff + 255) & ~(size_t)255;
    u32*   w1p      = (u32*)((char*)d_ws + wOff);
    u32*   w2p      = w1p + WPK;

    hipMemsetAsync(idx, 0xFF, idxBytes, stream);                        // idx = -1
    hipMemsetAsync(d_out, 0, (size_t)out_size * sizeof(float), stream); // dense zeros

    pack_kernel<<<(WPK + 255) / 256, 256, 0, stream>>>(w1, w2, w1p, w2p);
    scatter_idx_kernel<<<(n + 255) / 256, 256, 0, stream>>>(coors, idx, n);

    mid_kernel<<<512, 1024, 0, stream>>>(feat, idx, w1p, mid);
    out_kernel<<<512, 1024, 0, stream>>>(coors, mid, w2p, out, n);
}

// Round 5
// 648.248 us; speedup vs baseline: 2.4684x; 2.4684x over previous
//
#include <hip/hip_runtime.h>

// Problem constants (match reference)
#define D_   41
#define H_   159
#define W_   159
#define MD   20
#define MH   79
#define MW   79
#define CIN  32
#define COUT 64
#define BATCH 2

#define NTAP 27
#define PW   17                      // padded row (u32) per (tap,co): 16 ci-pairs + 1 pad
#define WLDS (NTAP * 64 * PW)        // 29,376 u32 = 117,504 B (fits 160 KB LDS)

typedef unsigned int u32;

static __device__ __forceinline__ u32 bf16_rn(float x) {
    u32 u = __float_as_uint(x);
    return (u + 0x7fffu + ((u >> 16) & 1u)) >> 16;   // round-to-nearest-even
}
static __device__ __forceinline__ float bf_lo(u32 p) { return __uint_as_float(p << 16); }
static __device__ __forceinline__ float bf_hi(u32 p) { return __uint_as_float(p & 0xffff0000u); }

// Pack w (fp32 [tap][ci][co]) -> padded [tap][co][PW] bf16-pairs (pair j = ci 2j,2j+1).
__global__ void pack_kernel(const float* __restrict__ w1, const float* __restrict__ w2,
                            u32* __restrict__ w1p, u32* __restrict__ w2p) {
    int i = blockIdx.x * 256 + threadIdx.x;
    if (i >= WLDS) return;
    int j = i % PW;
    int r = i / PW;                  // t*64 + co
    int co = r & 63, t = r >> 6;
    if (j >= 16) { w1p[i] = 0; w2p[i] = 0; return; }
    int s0 = (t * 32 + 2 * j) * 64 + co;
    int s1 = (t * 32 + 2 * j + 1) * 64 + co;
    w1p[i] = bf16_rn(w1[s0]) | (bf16_rn(w1[s1]) << 16);
    w2p[i] = bf16_rn(w2[s0]) | (bf16_rn(w2[s1]) << 16);
}

// Scatter point index into dense idx grid (-1 = empty).
__global__ void scatter_idx_kernel(const int* __restrict__ coors,
                                   int* __restrict__ idx, int n) {
    int i = blockIdx.x * blockDim.x + threadIdx.x;
    if (i >= n) return;
    int4 c = ((const int4*)coors)[i];
    idx[((c.x * D_ + c.y) * H_ + c.z) * W_ + c.w] = i;
}

// mid[b,zo,yo,xo,co]: one wave per voxel (contiguous chunks), lane = co.
// w1 in LDS (bf16 pairs, conflict-free stride 17); 27-tap lane-parallel probe + ballot.
__global__ __launch_bounds__(1024) void mid_kernel(const float* __restrict__ feat,
                                                   const int* __restrict__ idx,
                                                   const u32* __restrict__ w1p,
                                                   float* __restrict__ mid) {
    __shared__ u32 lw[WLDS];
    for (int i = threadIdx.x; i < WLDS; i += 1024) lw[i] = w1p[i];
    __syncthreads();

    const int NV = BATCH * MD * MH * MW;
    int lane = threadIdx.x & 63;
    int wid  = threadIdx.x >> 6;
    int nw   = gridDim.x * 16;
    int gw   = blockIdx.x * 16 + wid;
    int per  = (NV + nw - 1) / nw;
    int v0   = gw * per;
    int v1   = v0 + per; if (v1 > NV) v1 = NV;

    int l  = lane < NTAP ? lane : NTAP - 1;
    int kz = l / 9, kr = l % 9, ky = kr / 3, kx = kr % 3;

    for (int v = v0; v < v1; ++v) {
        int xo = v % MW; int t0 = v / MW;
        int yo = t0 % MH; t0 /= MH;
        int zo = t0 % MD; int b = t0 / MD;

        int p = -1;
        if (lane < NTAP)
            p = idx[((b * D_ + 2 * zo + kz) * H_ + 2 * yo + ky) * W_ + 2 * xo + kx];
        unsigned long long m = __ballot(p >= 0);

        float acc0 = 0.f, acc1 = 0.f;
        while (m) {
            int t = __builtin_ctzll(m);
            m &= m - 1;
            int pp = __shfl(p, t);                       // broadcast point index
            const float4* f4 = (const float4*)(feat + (size_t)pp * CIN);
            const u32* w = lw + (t * 64 + lane) * PW;    // 16 contiguous pairs
            #pragma unroll
            for (int jq = 0; jq < 8; ++jq) {
                float4 f = f4[jq];                       // 16B broadcast load
                u32 p0 = w[2 * jq + 0];                  // ci 4jq, 4jq+1
                u32 p1 = w[2 * jq + 1];                  // ci 4jq+2, 4jq+3
                acc0 = fmaf(f.x, bf_lo(p0), acc0);
                acc1 = fmaf(f.y, bf_hi(p0), acc1);
                acc0 = fmaf(f.z, bf_lo(p1), acc0);
                acc1 = fmaf(f.w, bf_hi(p1), acc1);
            }
        }
        mid[(size_t)v * COUT + lane] = acc0 + acc1;
    }
}

// Statically-unrolled butterfly reduce-scatter step (no dynamic indexing -> no spill).
#define BSTEP(MK, HALF)                                            \
    {                                                              \
        bool up = (lane & MK) != 0;                                \
        _Pragma("unroll")                                          \
        for (int k = 0; k < HALF; ++k) {                           \
            float send = up ? acc[k] : acc[k + HALF];              \
            float keep = up ? acc[k + HALF] : acc[k];              \
            acc[k] = keep + __shfl_xor(send, MK, 64);              \
        }                                                          \
    }

// out at masked voxels: one wave per point (contiguous chunks), lane = co.
// w2 in LDS; acc[32] (ci) reduced via static butterfly; lane pair -> one ci.
__global__ __launch_bounds__(1024) void out_kernel(const int* __restrict__ coors,
                                                   const float* __restrict__ mid,
                                                   const u32* __restrict__ w2p,
                                                   float* __restrict__ out, int n) {
    __shared__ u32 lw[WLDS];
    for (int i = threadIdx.x; i < WLDS; i += 1024) lw[i] = w2p[i];
    __syncthreads();

    int lane = threadIdx.x & 63;
    int wid  = threadIdx.x >> 6;
    int nw   = gridDim.x * 16;
    int gw   = blockIdx.x * 16 + wid;
    int per  = (n + nw - 1) / nw;
    int i0   = gw * per;
    int i1   = i0 + per; if (i1 > n) i1 = n;

    int l  = lane < NTAP ? lane : NTAP - 1;
    int kz = l / 9, kr = l % 9, ky = kr / 3, kx = kr % 3;

    for (int i = i0; i < i1; ++i) {
        int4 c = ((const int4*)coors)[i];
        int b = c.x, z = c.y, y = c.z, x = c.w;

        int zr = z - kz, yr = y - ky, xr = x - kx;
        bool ok = (lane < NTAP) &&
                  zr >= 0 && !(zr & 1) && (zr >> 1) < MD &&
                  yr >= 0 && !(yr & 1) && (yr >> 1) < MH &&
                  xr >= 0 && !(xr & 1) && (xr >> 1) < MW;
        int vv = ok ? ((b * MD + (zr >> 1)) * MH + (yr >> 1)) * MW + (xr >> 1) : -1;
        unsigned long long m = __ballot(ok);

        float acc[CIN];
        #pragma unroll
        for (int ci = 0; ci < CIN; ++ci) acc[ci] = 0.f;

        while (m) {
            int t = __builtin_ctzll(m);
            m &= m - 1;
            int v = __shfl(vv, t);
            float mr = mid[(size_t)v * COUT + lane];     // coalesced 256B
            const u32* w = lw + (t * 64 + lane) * PW;    // 16 contiguous pairs
            #pragma unroll
            for (int j = 0; j < 16; ++j) {
                u32 pw = w[j];
                acc[2 * j + 0] = fmaf(mr, bf_lo(pw), acc[2 * j + 0]);
                acc[2 * j + 1] = fmaf(mr, bf_hi(pw), acc[2 * j + 1]);
            }
        }

        // Reduce-scatter 32 ci over 64 lanes (co): 5 static butterfly steps.
        BSTEP(32, 16)
        BSTEP(16, 8)
        BSTEP(8, 4)
        BSTEP(4, 2)
        BSTEP(2, 1)
        float s = acc[0] + __shfl_xor(acc[0], 1, 64);
        if (!(lane & 1)) {
            int ci = lane >> 1;
            out[((size_t)(b * CIN + ci) * D_ + z) * (H_ * W_) + (size_t)y * W_ + x] = s;
        }
    }
}

extern "C" void kernel_launch(void* const* d_in, const int* in_sizes, int n_in,
                              void* d_out, int out_size, void* d_ws, size_t ws_size,
                              hipStream_t stream) {
    const float* feat  = (const float*)d_in[0];
    const int*   coors = (const int*)d_in[1];
    const float* w1    = (const float*)d_in[3];
    const float* w2    = (const float*)d_in[4];
    float*       out   = (float*)d_out;

    int n = in_sizes[0] / CIN;   // 150000 points total

    // Workspace: [idx 8.3MB][mid 64MB][w1p 117.5KB][w2p 117.5KB]
    int*   idx      = (int*)d_ws;
    size_t idxBytes = (size_t)BATCH * D_ * H_ * W_ * sizeof(int);
    size_t midOff   = (idxBytes + 255) & ~(size_t)255;
    float* mid      = (float*)((char*)d_ws + midOff);
    size_t wOff     = midOff + (size_t)BATCH * MD * MH * MW * COUT * sizeof(float);
    wOff            = (wOff + 255) & ~(size_t)255;
    u32*   w1p      = (u32*)((char*)d_ws + wOff);
    u32*   w2p      = w1p + WLDS;

    hipMemsetAsync(idx, 0xFF, idxBytes, stream);                        // idx = -1
    hipMemsetAsync(d_out, 0, (size_t)out_size * sizeof(float), stream); // dense zeros

    pack_kernel<<<(WLDS + 255) / 256, 256, 0, stream>>>(w1, w2, w1p, w2p);
    scatter_idx_kernel<<<(n + 255) / 256, 256, 0, stream>>>(coors, idx, n);

    mid_kernel<<<256, 1024, 0, stream>>>(feat, idx, w1p, mid);
    out_kernel<<<256, 1024, 0, stream>>>(coors, mid, w2p, out, n);
}

// Round 6
// 634.003 us; speedup vs baseline: 2.5238x; 1.0225x over previous
//
#include <hip/hip_runtime.h>

// Problem constants (match reference)
#define D_   41
#define H_   159
#define W_   159
#define MD   20
#define MH   79
#define MW   79
#define CIN  32
#define COUT 64
#define BATCH 2

#define NTAP 27
#define WLDS (NTAP * 16 * 64)   // packed weights [tap][j][co], u32 = ci-pair; 110,592 B

typedef unsigned int u32;

static __device__ __forceinline__ u32 bf16_rn(float x) {
    u32 u = __float_as_uint(x);
    return (u + 0x7fffu + ((u >> 16) & 1u)) >> 16;   // round-to-nearest-even
}
static __device__ __forceinline__ float bf_lo(u32 p) { return __uint_as_float(p << 16); }
static __device__ __forceinline__ float bf_hi(u32 p) { return __uint_as_float(p & 0xffff0000u); }

// Pack w (fp32 [tap][ci][co]) -> [tap][j][co] bf16-pairs (pair j = ci 2j,2j+1).
__global__ void pack_kernel(const float* __restrict__ w1, const float* __restrict__ w2,
                            u32* __restrict__ w1p, u32* __restrict__ w2p) {
    int i = blockIdx.x * 256 + threadIdx.x;
    if (i >= WLDS) return;
    int co = i & 63, j = (i >> 6) & 15, t = i >> 10;
    int s0 = (t * 32 + 2 * j) * 64 + co;
    int s1 = (t * 32 + 2 * j + 1) * 64 + co;
    w1p[i] = bf16_rn(w1[s0]) | (bf16_rn(w1[s1]) << 16);
    w2p[i] = bf16_rn(w2[s0]) | (bf16_rn(w2[s1]) << 16);
}

// Scatter point index into dense idx grid (-1 = empty).
__global__ void scatter_idx_kernel(const int* __restrict__ coors,
                                   int* __restrict__ idx, int n) {
    int i = blockIdx.x * blockDim.x + threadIdx.x;
    if (i >= n) return;
    int4 c = ((const int4*)coors)[i];
    idx[((c.x * D_ + c.y) * H_ + c.z) * W_ + c.w] = i;
}

// mid: one wave per voxel PAIR per iteration; probes for the next pair prefetched.
// Two independent event streams (A,B) interleaved for ILP; w1 in LDS.
__global__ __launch_bounds__(1024) void mid_kernel(const float* __restrict__ feat,
                                                   const int* __restrict__ idx,
                                                   const u32* __restrict__ w1p,
                                                   float* __restrict__ mid) {
    __shared__ u32 lw[WLDS];
    for (int i = threadIdx.x; i < WLDS; i += 1024) lw[i] = w1p[i];
    __syncthreads();

    const int NV = BATCH * MD * MH * MW;
    int lane = threadIdx.x & 63;
    int wid  = threadIdx.x >> 6;
    int nw   = gridDim.x * 16;
    int gw   = blockIdx.x * 16 + wid;
    int per  = (NV + nw - 1) / nw;
    int v0   = gw * per;
    int v1   = v0 + per; if (v1 > NV) v1 = NV;

    int l  = lane < NTAP ? lane : NTAP - 1;
    int kz = l / 9, kr = l % 9, ky = kr / 3, kx = kr % 3;

    auto probe = [&](int v) -> int {
        if (v >= v1 || lane >= NTAP) return -1;
        int xo = v % MW; int t0 = v / MW;
        int yo = t0 % MH; t0 /= MH;
        int zo = t0 % MD; int b = t0 / MD;
        return idx[((b * D_ + 2 * zo + kz) * H_ + 2 * yo + ky) * W_ + 2 * xo + kx];
    };

    int pA = probe(v0), pB = probe(v0 + 1);
    for (int v = v0; v < v1; v += 2) {
        int cA = pA, cB = pB;
        pA = probe(v + 2);            // prefetch next pair's probes
        pB = probe(v + 3);
        unsigned long long mA = __ballot(cA >= 0);
        unsigned long long mB = __ballot(cB >= 0);

        float a0 = 0.f, a1 = 0.f, b0 = 0.f, b1 = 0.f;
        while (mA | mB) {
            bool hA = mA != 0, hB = mB != 0;   // wave-uniform
            float4 fav[8], fbv[8];
            u32 wav[16], wbv[16];
            if (hA) {
                int t = (int)__builtin_ctzll(mA); mA &= mA - 1;
                int pp = __shfl(cA, t);
                const float4* f4 = (const float4*)(feat + (size_t)pp * CIN);
                const u32* w = lw + (t * 16) * 64 + lane;
                #pragma unroll
                for (int q = 0; q < 8; ++q) fav[q] = f4[q];
                #pragma unroll
                for (int j = 0; j < 16; ++j) wav[j] = w[j * 64];
            }
            if (hB) {
                int t = (int)__builtin_ctzll(mB); mB &= mB - 1;
                int pp = __shfl(cB, t);
                const float4* f4 = (const float4*)(feat + (size_t)pp * CIN);
                const u32* w = lw + (t * 16) * 64 + lane;
                #pragma unroll
                for (int q = 0; q < 8; ++q) fbv[q] = f4[q];
                #pragma unroll
                for (int j = 0; j < 16; ++j) wbv[j] = w[j * 64];
            }
            if (hA) {
                #pragma unroll
                for (int q = 0; q < 8; ++q) {
                    a0 = fmaf(fav[q].x, bf_lo(wav[2 * q + 0]), a0);
                    a1 = fmaf(fav[q].y, bf_hi(wav[2 * q + 0]), a1);
                    a0 = fmaf(fav[q].z, bf_lo(wav[2 * q + 1]), a0);
                    a1 = fmaf(fav[q].w, bf_hi(wav[2 * q + 1]), a1);
                }
            }
            if (hB) {
                #pragma unroll
                for (int q = 0; q < 8; ++q) {
                    b0 = fmaf(fbv[q].x, bf_lo(wbv[2 * q + 0]), b0);
                    b1 = fmaf(fbv[q].y, bf_hi(wbv[2 * q + 0]), b1);
                    b0 = fmaf(fbv[q].z, bf_lo(wbv[2 * q + 1]), b0);
                    b1 = fmaf(fbv[q].w, bf_hi(wbv[2 * q + 1]), b1);
                }
            }
        }
        mid[(size_t)v * COUT + lane] = a0 + a1;
        if (v + 1 < v1) mid[(size_t)(v + 1) * COUT + lane] = b0 + b1;
    }
}

// Statically-unrolled butterfly reduce-scatter step (no dynamic indexing -> no spill).
#define BSTEP(MK, HALF)                                            \
    {                                                              \
        bool up = (lane & MK) != 0;                                \
        _Pragma("unroll")                                          \
        for (int k = 0; k < HALF; ++k) {                           \
            float send = up ? acc[k] : acc[k + HALF];              \
            float keep = up ? acc[k + HALF] : acc[k];              \
            acc[k] = keep + __shfl_xor(send, MK, 64);              \
        }                                                          \
    }

// out: one wave per point; coors prefetched; events processed in PAIRS
// (both events' loads issued before either FMA block). w2 in LDS.
__global__ __launch_bounds__(1024) void out_kernel(const int* __restrict__ coors,
                                                   const float* __restrict__ mid,
                                                   const u32* __restrict__ w2p,
                                                   float* __restrict__ out, int n) {
    __shared__ u32 lw[WLDS];
    for (int i = threadIdx.x; i < WLDS; i += 1024) lw[i] = w2p[i];
    __syncthreads();

    int lane = threadIdx.x & 63;
    int wid  = threadIdx.x >> 6;
    int nw   = gridDim.x * 16;
    int gw   = blockIdx.x * 16 + wid;
    int per  = (n + nw - 1) / nw;
    int i0   = gw * per;
    int i1   = i0 + per; if (i1 > n) i1 = n;

    int l  = lane < NTAP ? lane : NTAP - 1;
    int kz = l / 9, kr = l % 9, ky = kr / 3, kx = kr % 3;

    const int4* cvec = (const int4*)coors;
    int4 nc = make_int4(0, 0, 0, 0);
    if (i0 < i1) nc = cvec[i0];

    for (int i = i0; i < i1; ++i) {
        int4 c = nc;
        if (i + 1 < i1) nc = cvec[i + 1];   // prefetch next point
        int b = c.x, z = c.y, y = c.z, x = c.w;

        int zr = z - kz, yr = y - ky, xr = x - kx;
        bool ok = (lane < NTAP) &&
                  zr >= 0 && !(zr & 1) && (zr >> 1) < MD &&
                  yr >= 0 && !(yr & 1) && (yr >> 1) < MH &&
                  xr >= 0 && !(xr & 1) && (xr >> 1) < MW;
        int vv = ok ? ((b * MD + (zr >> 1)) * MH + (yr >> 1)) * MW + (xr >> 1) : -1;
        unsigned long long m = __ballot(ok);

        float acc[CIN];
        #pragma unroll
        for (int ci = 0; ci < CIN; ++ci) acc[ci] = 0.f;

        while (m) {
            int t0 = (int)__builtin_ctzll(m); m &= m - 1;
            bool h1 = (m != 0);               // wave-uniform
            int t1 = 0;
            if (h1) { t1 = (int)__builtin_ctzll(m); m &= m - 1; }

            int ve0 = __shfl(vv, t0);
            float mr0 = mid[(size_t)ve0 * COUT + lane];
            u32 wv0[16];
            const u32* w0 = lw + (t0 * 16) * 64 + lane;
            #pragma unroll
            for (int j = 0; j < 16; ++j) wv0[j] = w0[j * 64];

            float mr1 = 0.f; u32 wv1[16];
            if (h1) {
                int ve1 = __shfl(vv, t1);
                mr1 = mid[(size_t)ve1 * COUT + lane];
                const u32* w1_ = lw + (t1 * 16) * 64 + lane;
                #pragma unroll
                for (int j = 0; j < 16; ++j) wv1[j] = w1_[j * 64];
            }

            #pragma unroll
            for (int j = 0; j < 16; ++j) {
                acc[2 * j + 0] = fmaf(mr0, bf_lo(wv0[j]), acc[2 * j + 0]);
                acc[2 * j + 1] = fmaf(mr0, bf_hi(wv0[j]), acc[2 * j + 1]);
            }
            if (h1) {
                #pragma unroll
                for (int j = 0; j < 16; ++j) {
                    acc[2 * j + 0] = fmaf(mr1, bf_lo(wv1[j]), acc[2 * j + 0]);
                    acc[2 * j + 1] = fmaf(mr1, bf_hi(wv1[j]), acc[2 * j + 1]);
                }
            }
        }

        // Reduce-scatter 32 ci over 64 lanes (co): 5 static butterfly steps.
        BSTEP(32, 16)
        BSTEP(16, 8)
        BSTEP(8, 4)
        BSTEP(4, 2)
        BSTEP(2, 1)
        float s = acc[0] + __shfl_xor(acc[0], 1, 64);
        if (!(lane & 1)) {
            int ci = lane >> 1;
            out[((size_t)(b * CIN + ci) * D_ + z) * (H_ * W_) + (size_t)y * W_ + x] = s;
        }
    }
}

extern "C" void kernel_launch(void* const* d_in, const int* in_sizes, int n_in,
                              void* d_out, int out_size, void* d_ws, size_t ws_size,
                              hipStream_t stream) {
    const float* feat  = (const float*)d_in[0];
    const int*   coors = (const int*)d_in[1];
    const float* w1    = (const float*)d_in[3];
    const float* w2    = (const float*)d_in[4];
    float*       out   = (float*)d_out;

    int n = in_sizes[0] / CIN;   // 150000 points total

    // Workspace: [idx 8.3MB][mid 64MB][w1p 110.6KB][w2p 110.6KB]
    int*   idx      = (int*)d_ws;
    size_t idxBytes = (size_t)BATCH * D_ * H_ * W_ * sizeof(int);
    size_t midOff   = (idxBytes + 255) & ~(size_t)255;
    float* mid      = (float*)((char*)d_ws + midOff);
    size_t wOff     = midOff + (size_t)BATCH * MD * MH * MW * COUT * sizeof(float);
    wOff            = (wOff + 255) & ~(size_t)255;
    u32*   w1p      = (u32*)((char*)d_ws + wOff);
    u32*   w2p      = w1p + WLDS;

    hipMemsetAsync(idx, 0xFF, idxBytes, stream);                        // idx = -1
    hipMemsetAsync(d_out, 0, (size_t)out_size * sizeof(float), stream); // dense zeros

    pack_kernel<<<(WLDS + 255) / 256, 256, 0, stream>>>(w1, w2, w1p, w2p);
    scatter_idx_kernel<<<(n + 255) / 256, 256, 0, stream>>>(coors, idx, n);

    mid_kernel<<<256, 1024, 0, stream>>>(feat, idx, w1p, mid);
    out_kernel<<<256, 1024, 0, stream>>>(coors, mid, w2p, out, n);
}

// Round 7
// 633.502 us; speedup vs baseline: 2.5258x; 1.0008x over previous
//
#include <hip/hip_runtime.h>

// Problem constants (match reference)
#define D_   41
#define H_   159
#define W_   159
#define MD   20
#define MH   79
#define MW   79
#define CIN  32
#define COUT 64
#define BATCH 2

#define NTAP 27
// LDS weights: [tap][j4][co][4], u32 = bf16 ci-pair. Lane co reads 16B contiguous
// at ((t*4+j4)*64+co)*16 -> conflict-free ds_read_b128. 27*16*64*4 = 110,592 B.
#define WLDS (NTAP * 16 * 64)

typedef unsigned int u32;

static __device__ __forceinline__ u32 bf16_rn(float x) {
    u32 u = __float_as_uint(x);
    return (u + 0x7fffu + ((u >> 16) & 1u)) >> 16;   // round-to-nearest-even
}
static __device__ __forceinline__ float bf_lo(u32 p) { return __uint_as_float(p << 16); }
static __device__ __forceinline__ float bf_hi(u32 p) { return __uint_as_float(p & 0xffff0000u); }

// Pack w (fp32 [tap][ci][co]) -> [tap][j4][co][k] bf16-pairs (pair j=4*j4+k = ci 2j,2j+1).
__global__ void pack_kernel(const float* __restrict__ w1, const float* __restrict__ w2,
                            u32* __restrict__ w1p, u32* __restrict__ w2p) {
    int i = blockIdx.x * 256 + threadIdx.x;
    if (i >= WLDS) return;
    int k  = i & 3;
    int co = (i >> 2) & 63;
    int j4 = (i >> 8) & 3;
    int t  = i >> 10;
    int j  = j4 * 4 + k;
    int s0 = (t * 32 + 2 * j) * 64 + co;
    int s1 = (t * 32 + 2 * j + 1) * 64 + co;
    w1p[i] = bf16_rn(w1[s0]) | (bf16_rn(w1[s1]) << 16);
    w2p[i] = bf16_rn(w2[s0]) | (bf16_rn(w2[s1]) << 16);
}

// Scatter point index into dense idx grid (-1 = empty).
__global__ void scatter_idx_kernel(const int* __restrict__ coors,
                                   int* __restrict__ idx, int n) {
    int i = blockIdx.x * blockDim.x + threadIdx.x;
    if (i >= n) return;
    int4 c = ((const int4*)coors)[i];
    idx[((c.x * D_ + c.y) * H_ + c.z) * W_ + c.w] = i;
}

// Load one event's 16 weight pairs via 4 conflict-free ds_read_b128.
#define LOADW(dst, t)                                              \
    {                                                              \
        const uint4* wq = (const uint4*)lw + (t) * 256 + lane;     \
        uint4 q0 = wq[0], q1 = wq[64], q2 = wq[128], q3 = wq[192]; \
        dst[0] = q0.x;  dst[1] = q0.y;  dst[2] = q0.z;  dst[3] = q0.w;   \
        dst[4] = q1.x;  dst[5] = q1.y;  dst[6] = q1.z;  dst[7] = q1.w;   \
        dst[8] = q2.x;  dst[9] = q2.y;  dst[10] = q2.z; dst[11] = q2.w;  \
        dst[12] = q3.x; dst[13] = q3.y; dst[14] = q3.z; dst[15] = q3.w;  \
    }

// mid: one wave per voxel PAIR per iteration; probes prefetched; two event
// streams interleaved; w1 in LDS read as b128.
__global__ __launch_bounds__(1024) void mid_kernel(const float* __restrict__ feat,
                                                   const int* __restrict__ idx,
                                                   const u32* __restrict__ w1p,
                                                   float* __restrict__ mid) {
    __shared__ u32 lw[WLDS];
    for (int i = threadIdx.x; i < WLDS; i += 1024) lw[i] = w1p[i];
    __syncthreads();

    const int NV = BATCH * MD * MH * MW;
    int lane = threadIdx.x & 63;
    int wid  = threadIdx.x >> 6;
    int nw   = gridDim.x * 16;
    int gw   = blockIdx.x * 16 + wid;
    int per  = (NV + nw - 1) / nw;
    int v0   = gw * per;
    int v1   = v0 + per; if (v1 > NV) v1 = NV;

    int l  = lane < NTAP ? lane : NTAP - 1;
    int kz = l / 9, kr = l % 9, ky = kr / 3, kx = kr % 3;

    auto probe = [&](int v) -> int {
        if (v >= v1 || lane >= NTAP) return -1;
        int xo = v % MW; int t0 = v / MW;
        int yo = t0 % MH; t0 /= MH;
        int zo = t0 % MD; int b = t0 / MD;
        return idx[((b * D_ + 2 * zo + kz) * H_ + 2 * yo + ky) * W_ + 2 * xo + kx];
    };

    int pA = probe(v0), pB = probe(v0 + 1);
    for (int v = v0; v < v1; v += 2) {
        int cA = pA, cB = pB;
        pA = probe(v + 2);            // prefetch next pair's probes
        pB = probe(v + 3);
        unsigned long long mA = __ballot(cA >= 0);
        unsigned long long mB = __ballot(cB >= 0);

        float a0 = 0.f, a1 = 0.f, b0 = 0.f, b1 = 0.f;
        while (mA | mB) {
            bool hA = mA != 0, hB = mB != 0;   // wave-uniform
            float4 fav[8], fbv[8];
            u32 wav[16], wbv[16];
            if (hA) {
                int t = (int)__builtin_ctzll(mA); mA &= mA - 1;
                int pp = __shfl(cA, t);
                const float4* f4 = (const float4*)(feat + (size_t)pp * CIN);
                #pragma unroll
                for (int q = 0; q < 8; ++q) fav[q] = f4[q];
                LOADW(wav, t)
            }
            if (hB) {
                int t = (int)__builtin_ctzll(mB); mB &= mB - 1;
                int pp = __shfl(cB, t);
                const float4* f4 = (const float4*)(feat + (size_t)pp * CIN);
                #pragma unroll
                for (int q = 0; q < 8; ++q) fbv[q] = f4[q];
                LOADW(wbv, t)
            }
            if (hA) {
                #pragma unroll
                for (int q = 0; q < 8; ++q) {
                    a0 = fmaf(fav[q].x, bf_lo(wav[2 * q + 0]), a0);
                    a1 = fmaf(fav[q].y, bf_hi(wav[2 * q + 0]), a1);
                    a0 = fmaf(fav[q].z, bf_lo(wav[2 * q + 1]), a0);
                    a1 = fmaf(fav[q].w, bf_hi(wav[2 * q + 1]), a1);
                }
            }
            if (hB) {
                #pragma unroll
                for (int q = 0; q < 8; ++q) {
                    b0 = fmaf(fbv[q].x, bf_lo(wbv[2 * q + 0]), b0);
                    b1 = fmaf(fbv[q].y, bf_hi(wbv[2 * q + 0]), b1);
                    b0 = fmaf(fbv[q].z, bf_lo(wbv[2 * q + 1]), b0);
                    b1 = fmaf(fbv[q].w, bf_hi(wbv[2 * q + 1]), b1);
                }
            }
        }
        mid[(size_t)v * COUT + lane] = a0 + a1;
        if (v + 1 < v1) mid[(size_t)(v + 1) * COUT + lane] = b0 + b1;
    }
}

// Statically-unrolled butterfly reduce-scatter step (no dynamic indexing -> no spill).
#define BSTEP(MK, HALF)                                            \
    {                                                              \
        bool up = (lane & MK) != 0;                                \
        _Pragma("unroll")                                          \
        for (int k = 0; k < HALF; ++k) {                           \
            float send = up ? acc[k] : acc[k + HALF];              \
            float keep = up ? acc[k + HALF] : acc[k];              \
            acc[k] = keep + __shfl_xor(send, MK, 64);              \
        }                                                          \
    }

// out: one wave per point; coors prefetched; events in PAIRS; w2 in LDS (b128).
__global__ __launch_bounds__(1024) void out_kernel(const int* __restrict__ coors,
                                                   const float* __restrict__ mid,
                                                   const u32* __restrict__ w2p,
                                                   float* __restrict__ out, int n) {
    __shared__ u32 lw[WLDS];
    for (int i = threadIdx.x; i < WLDS; i += 1024) lw[i] = w2p[i];
    __syncthreads();

    int lane = threadIdx.x & 63;
    int wid  = threadIdx.x >> 6;
    int nw   = gridDim.x * 16;
    int gw   = blockIdx.x * 16 + wid;
    int per  = (n + nw - 1) / nw;
    int i0   = gw * per;
    int i1   = i0 + per; if (i1 > n) i1 = n;

    int l  = lane < NTAP ? lane : NTAP - 1;
    int kz = l / 9, kr = l % 9, ky = kr / 3, kx = kr % 3;

    const int4* cvec = (const int4*)coors;
    int4 nc = make_int4(0, 0, 0, 0);
    if (i0 < i1) nc = cvec[i0];

    for (int i = i0; i < i1; ++i) {
        int4 c = nc;
        if (i + 1 < i1) nc = cvec[i + 1];   // prefetch next point
        int b = c.x, z = c.y, y = c.z, x = c.w;

        int zr = z - kz, yr = y - ky, xr = x - kx;
        bool ok = (lane < NTAP) &&
                  zr >= 0 && !(zr & 1) && (zr >> 1) < MD &&
                  yr >= 0 && !(yr & 1) && (yr >> 1) < MH &&
                  xr >= 0 && !(xr & 1) && (xr >> 1) < MW;
        int vv = ok ? ((b * MD + (zr >> 1)) * MH + (yr >> 1)) * MW + (xr >> 1) : -1;
        unsigned long long m = __ballot(ok);

        float acc[CIN];
        #pragma unroll
        for (int ci = 0; ci < CIN; ++ci) acc[ci] = 0.f;

        while (m) {
            int t0 = (int)__builtin_ctzll(m); m &= m - 1;
            bool h1 = (m != 0);               // wave-uniform
            int t1 = 0;
            if (h1) { t1 = (int)__builtin_ctzll(m); m &= m - 1; }

            int ve0 = __shfl(vv, t0);
            float mr0 = mid[(size_t)ve0 * COUT + lane];
            u32 wv0[16];
            LOADW(wv0, t0)

            float mr1 = 0.f; u32 wv1[16];
            if (h1) {
                int ve1 = __shfl(vv, t1);
                mr1 = mid[(size_t)ve1 * COUT + lane];
                LOADW(wv1, t1)
            }

            #pragma unroll
            for (int j = 0; j < 16; ++j) {
                acc[2 * j + 0] = fmaf(mr0, bf_lo(wv0[j]), acc[2 * j + 0]);
                acc[2 * j + 1] = fmaf(mr0, bf_hi(wv0[j]), acc[2 * j + 1]);
            }
            if (h1) {
                #pragma unroll
                for (int j = 0; j < 16; ++j) {
                    acc[2 * j + 0] = fmaf(mr1, bf_lo(wv1[j]), acc[2 * j + 0]);
                    acc[2 * j + 1] = fmaf(mr1, bf_hi(wv1[j]), acc[2 * j + 1]);
                }
            }
        }

        // Reduce-scatter 32 ci over 64 lanes (co): 5 static butterfly steps.
        BSTEP(32, 16)
        BSTEP(16, 8)
        BSTEP(8, 4)
        BSTEP(4, 2)
        BSTEP(2, 1)
        float s = acc[0] + __shfl_xor(acc[0], 1, 64);
        if (!(lane & 1)) {
            int ci = lane >> 1;
            out[((size_t)(b * CIN + ci) * D_ + z) * (H_ * W_) + (size_t)y * W_ + x] = s;
        }
    }
}

extern "C" void kernel_launch(void* const* d_in, const int* in_sizes, int n_in,
                              void* d_out, int out_size, void* d_ws, size_t ws_size,
                              hipStream_t stream) {
    const float* feat  = (const float*)d_in[0];
    const int*   coors = (const int*)d_in[1];
    const float* w1    = (const float*)d_in[3];
    const float* w2    = (const float*)d_in[4];
    float*       out   = (float*)d_out;

    int n = in_sizes[0] / CIN;   // 150000 points total

    // Workspace: [idx 8.3MB][mid 64MB][w1p 110.6KB][w2p 110.6KB]
    int*   idx      = (int*)d_ws;
    size_t idxBytes = (size_t)BATCH * D_ * H_ * W_ * sizeof(int);
    size_t midOff   = (idxBytes + 255) & ~(size_t)255;
    float* mid      = (float*)((char*)d_ws + midOff);
    size_t wOff     = midOff + (size_t)BATCH * MD * MH * MW * COUT * sizeof(float);
    wOff            = (wOff + 255) & ~(size_t)255;
    u32*   w1p      = (u32*)((char*)d_ws + wOff);
    u32*   w2p      = w1p + WLDS;

    hipMemsetAsync(idx, 0xFF, idxBytes, stream);                        // idx = -1
    hipMemsetAsync(d_out, 0, (size_t)out_size * sizeof(float), stream); // dense zeros

    pack_kernel<<<(WLDS + 255) / 256, 256, 0, stream>>>(w1, w2, w1p, w2p);
    scatter_idx_kernel<<<(n + 255) / 256, 256, 0, stream>>>(coors, idx, n);

    mid_kernel<<<256, 1024, 0, stream>>>(feat, idx, w1p, mid);
    out_kernel<<<256, 1024, 0, stream>>>(coors, mid, w2p, out, n);
}